// Round 3
// baseline (201.272 us; speedup 1.0000x reference)
//
#include <hip/hip_runtime.h>
#include <hip/hip_bf16.h>
#include <math.h>

typedef float v4f __attribute__((ext_vector_type(4)));
typedef __bf16 bf16x8 __attribute__((ext_vector_type(8)));
typedef __bf16 bf16x4 __attribute__((ext_vector_type(4)));
typedef short  s4v   __attribute__((ext_vector_type(4)));

#define NN   1024
#define INF  128
#define H0C  192
#define H1C  96

// ws byte offsets
#define WS_W0BF   0        // 24576 bf16 = 49152 B  (16x16x32 A-frag order, BN0 scale folded)
#define WS_W1BF   49152    // 18432 bf16 = 36864 B  (16x16x16 A-frag order, BN1 scale folded)
#define WS_BN0SW  86016    // 192 f32: [q][ct][r] = bn0b[16ct+4q+r]
#define WS_BN1SW  86784    // 96 f32:  [q][dt][r] = bn1b[16dt+4q+r]
#define WS_WOUTSW 87168    // 96 f32:  [q][dt][r] = wout[16dt+4q+r]
#define WS_CINV   87552    // 1024 f32
#define WS_PART   91648    // 16*1024 f32 column partial sums

union bf4cast { bf16x4 b; s4v s; };

// ---------------------------------------------------------------------------
// Prep: swizzle weights into MFMA A-fragment orders (bf16), BN scale folded;
// biases/wout pre-swizzled per (quad, tile, reg).
// W0 (16x16x32 A-frag): lane holds A[m=l16][k=q*8+j], flat [(ct*4+ks)*64+lane]*8+j
// W1 (16x16x16 A-frag): lane holds A[m=l16][k=q*4+j], flat [(dt*12+ct)*64+lane]*4+j
// ---------------------------------------------------------------------------
__global__ __launch_bounds__(256) void prep_kernel(
    const float* __restrict__ W0, const float* __restrict__ g0,
    const float* __restrict__ b0, const float* __restrict__ m0,
    const float* __restrict__ v0, const float* __restrict__ W1,
    const float* __restrict__ g1, const float* __restrict__ b1,
    const float* __restrict__ m1, const float* __restrict__ v1,
    const float* __restrict__ Wout, char* __restrict__ ws)
{
    int e = blockIdx.x * 256 + threadIdx.x;
    __bf16* w0bf = (__bf16*)(ws + WS_W0BF);
    __bf16* w1bf = (__bf16*)(ws + WS_W1BF);
    float* bn0sw = (float*)(ws + WS_BN0SW);
    float* bn1sw = (float*)(ws + WS_BN1SW);
    float* woutsw = (float*)(ws + WS_WOUTSW);
    if (e < 24576) {                       // W0: 12 ct x 4 ks
        int j = e & 7, lane = (e >> 3) & 63, t = e >> 9;
        int ks = t & 3, ct = t >> 2;
        int c = ct * 16 + (lane & 15);               // m = H0 channel
        int k = ks * 32 + ((lane >> 4) << 3) + j;    // k = input feature
        float s = g0[c] * rsqrtf(v0[c] + 1e-5f);
        w0bf[e] = (__bf16)(W0[c * INF + k] * s);
    } else if (e < 43008) {                // W1: 6 dt x 12 ct (K=16 frags)
        int e2 = e - 24576;
        int j = e2 & 3, lane = (e2 >> 2) & 63, t = e2 >> 8;   // t in [0,72)
        int ct = t % 12, dt = t / 12;
        int d = dt * 16 + (lane & 15);               // m = H1 channel
        int c = ct * 16 + ((lane >> 4) << 2) + j;    // k = H0 channel
        float s = g1[d] * rsqrtf(v1[d] + 1e-5f);
        w1bf[e2] = (__bf16)(W1[d * H0C + c] * s);
    } else if (e < 43200) {                // bn0 bias swizzled [q][ct][r]
        int e3 = e - 43008;
        int q = e3 / 48, rem = e3 % 48, ct = rem >> 2, r = rem & 3;
        int c = ct * 16 + q * 4 + r;
        float s = g0[c] * rsqrtf(v0[c] + 1e-5f);
        bn0sw[e3] = b0[c] - m0[c] * s;
    } else if (e < 43296) {                // bn1 bias swizzled [q][dt][r]
        int e4 = e - 43200;
        int q = e4 / 24, rem = e4 % 24, dt = rem >> 2, r = rem & 3;
        int d = dt * 16 + q * 4 + r;
        float s = g1[d] * rsqrtf(v1[d] + 1e-5f);
        bn1sw[e4] = b1[d] - m1[d] * s;
    } else if (e < 43392) {                // wout swizzled [q][dt][r]
        int e5 = e - 43296;
        int q = e5 / 24, rem = e5 % 24, dt = rem >> 2, r = rem & 3;
        woutsw[e5] = Wout[dt * 16 + q * 4 + r];
    }
}

// ---------------------------------------------------------------------------
// Main fused kernel, transposed dataflow (pairs = MFMA n-dim), ZERO LDS,
// ZERO barriers. Block = 256 thr = 4 waves; block tile = 16 i x 16 j;
// wave w owns j-columns j0+4w .. j0+4w+3 (NT=4 ntiles of 16 pairs).
// Layer1: H0^T tiles via mfma_16x16x32 (A=W0 frags, B=X frags in registers).
// Layer1 C-layout == layer2 16x16x16 B-frag layout -> no transform at all.
// Symmetry: only bj>=bi tiles launched; both sim[i][j] and sim[j][i] stored.
// ---------------------------------------------------------------------------
__global__ __launch_bounds__(256, 2) void edgenet_main(
    const float* __restrict__ feat, const char* __restrict__ ws,
    const float* __restrict__ boutp, float* __restrict__ sim_out)
{
    const int tid = threadIdx.x;
    const int lane = tid & 63;
    const int wave = tid >> 6;
    const int l16 = lane & 15;
    const int quad = lane >> 4;

    // decode triangular tile id -> (bi, bj), bj >= bi, 64x64 grid of 16-tiles
    // cum(bi) = bi*(129-bi)/2
    const int id = blockIdx.x;
    int bi = (int)((129.0f - sqrtf(16641.0f - 8.0f * (float)id)) * 0.5f);
    if (bi > 63) bi = 63;
    while (bi > 0 && bi * (129 - bi) / 2 > id) --bi;
    while ((bi + 1) * (128 - bi) / 2 <= id) ++bi;
    const int bj = bi + (id - bi * (129 - bi) / 2);
    const int i0 = bi << 4;
    const int j0 = bj << 4;
    const int jjb = j0 + wave * 4;

    // ---- X B-fragments in registers: xf[ks][nt], lane = X[pair=l16][32ks+8q+j]
    bf16x8 xf[4][4];
    #pragma unroll
    for (int ks = 0; ks < 4; ++ks) {
        const float* fi = feat + (i0 + l16) * INF + ks * 32 + quad * 8;
        float4 a0 = *(const float4*)fi;
        float4 a1 = *(const float4*)(fi + 4);
        #pragma unroll
        for (int nt = 0; nt < 4; ++nt) {
            const float* fj = feat + (jjb + nt) * INF + ks * 32 + quad * 8;
            float4 q0 = *(const float4*)fj;
            float4 q1 = *(const float4*)(fj + 4);
            bf16x8 x;
            x[0] = (__bf16)fabsf(a0.x - q0.x);
            x[1] = (__bf16)fabsf(a0.y - q0.y);
            x[2] = (__bf16)fabsf(a0.z - q0.z);
            x[3] = (__bf16)fabsf(a0.w - q0.w);
            x[4] = (__bf16)fabsf(a1.x - q1.x);
            x[5] = (__bf16)fabsf(a1.y - q1.y);
            x[6] = (__bf16)fabsf(a1.z - q1.z);
            x[7] = (__bf16)fabsf(a1.w - q1.w);
            xf[ks][nt] = x;
        }
    }

    // ---- acc2 init with bn1 bias (C-layout row = 16dt+4q+r) ----
    const float* bn1sw = (const float*)(ws + WS_BN1SW);
    v4f acc2[4][6];
    #pragma unroll
    for (int dt = 0; dt < 6; ++dt) {
        v4f bb = *(const v4f*)(bn1sw + (quad * 6 + dt) * 4);
        #pragma unroll
        for (int nt = 0; nt < 4; ++nt)
            acc2[nt][dt] = bb;
    }

    // ---- main ct loop: layer1 (K=128) then immediately layer2 K-chunk ct ----
    const bf16x8* w0v = (const bf16x8*)(ws + WS_W0BF);
    const __bf16* w1p = (const __bf16*)(ws + WS_W1BF);
    const float* bn0sw = (const float*)(ws + WS_BN0SW);
    #pragma unroll
    for (int ct = 0; ct < 12; ++ct) {
        v4f b0v = *(const v4f*)(bn0sw + (quad * 12 + ct) * 4);
        v4f a1[4];
        {   // ks = 0 folds the bias as the MFMA C operand
            bf16x8 w = w0v[(ct * 4 + 0) * 64 + lane];
            #pragma unroll
            for (int nt = 0; nt < 4; ++nt)
                a1[nt] = __builtin_amdgcn_mfma_f32_16x16x32_bf16(
                    w, xf[0][nt], b0v, 0, 0, 0);
        }
        #pragma unroll
        for (int ks = 1; ks < 4; ++ks) {
            bf16x8 w = w0v[(ct * 4 + ks) * 64 + lane];
            #pragma unroll
            for (int nt = 0; nt < 4; ++nt)
                a1[nt] = __builtin_amdgcn_mfma_f32_16x16x32_bf16(
                    w, xf[ks][nt], a1[nt], 0, 0, 0);
        }
        // leaky + pack -> layer2 B-frags (C-layout reg r == B-frag j; no xform)
        s4v b2[4];
        #pragma unroll
        for (int nt = 0; nt < 4; ++nt) {
            bf4cast u;
            #pragma unroll
            for (int r = 0; r < 4; ++r) {
                float v = a1[nt][r];
                v = fmaxf(v, 0.01f * v);
                u.b[r] = (__bf16)v;
            }
            b2[nt] = u.s;
        }
        // layer2 accumulate: K-chunk = ct (16 channels)
        #pragma unroll
        for (int dt = 0; dt < 6; ++dt) {
            s4v w1f = *(const s4v*)(w1p + ((dt * 12 + ct) * 64 + lane) * 4);
            #pragma unroll
            for (int nt = 0; nt < 4; ++nt)
                acc2[nt][dt] = __builtin_amdgcn_mfma_f32_16x16x16bf16_1k(
                    w1f, b2[nt], acc2[nt][dt], 0, 0, 0);
        }
    }

    // ---- epilogue: leaky + dot(wout) + cross-quad reduce + sigmoid ----
    const float* woutsw = (const float*)(ws + WS_WOUTSW);
    float part[4] = {0.f, 0.f, 0.f, 0.f};
    #pragma unroll
    for (int dt = 0; dt < 6; ++dt) {
        v4f wo = *(const v4f*)(woutsw + (quad * 6 + dt) * 4);
        #pragma unroll
        for (int nt = 0; nt < 4; ++nt) {
            #pragma unroll
            for (int r = 0; r < 4; ++r) {
                float v = acc2[nt][dt][r];
                v = fmaxf(v, 0.01f * v);
                part[nt] = fmaf(v, wo[r], part[nt]);
            }
        }
    }
    #pragma unroll
    for (int nt = 0; nt < 4; ++nt) {
        part[nt] += __shfl_xor(part[nt], 16, 64);
        part[nt] += __shfl_xor(part[nt], 32, 64);
    }
    // quad q stores ntile q (pair (i0+l16, jjb+q)), direct + mirror
    float sel = quad < 2 ? (quad == 0 ? part[0] : part[1])
                         : (quad == 2 ? part[2] : part[3]);
    float logit = sel + boutp[0];
    float sv = 1.f / (1.f + expf(-logit));
    const int irow = i0 + l16;
    const int jcol = jjb + quad;
    sim_out[irow * NN + jcol] = sv;          // direct (16B chunks per l16 group)
    sim_out[jcol * NN + irow] = sv;          // mirror (64B contiguous per quad)
}

// ---------------------------------------------------------------------------
// Column partial sums: grid(16 jgroups, 16 igroups).
// ---------------------------------------------------------------------------
__global__ __launch_bounds__(256) void colsum_kernel(
    const float* __restrict__ sim, float* __restrict__ part)
{
    __shared__ float red[4][64];
    int jl = threadIdx.x & 63;
    int ig = threadIdx.x >> 6;
    int j = blockIdx.x * 64 + jl;
    int ibase = blockIdx.y * 64 + ig * 16;
    float s = 0.f;
    #pragma unroll
    for (int r = 0; r < 16; ++r)
        s += sim[(ibase + r) * NN + j];
    red[ig][jl] = s;
    __syncthreads();
    if (ig == 0) {
        float t = red[0][jl] + red[1][jl] + red[2][jl] + red[3][jl];
        part[blockIdx.y * NN + j] = t;
    }
}

__global__ __launch_bounds__(256) void finalize_kernel(
    const float* __restrict__ part, float* __restrict__ cinv)
{
    int j = blockIdx.x * 256 + threadIdx.x;
    float s = 0.f;
    #pragma unroll
    for (int p = 0; p < 16; ++p)
        s += part[p * NN + j];
    cinv[j] = 1.0f / (s + 1.0f + (float)NN * 1e-6f);
}

__global__ __launch_bounds__(256) void edge_kernel(
    const float* __restrict__ sim, const float* __restrict__ cinv,
    float* __restrict__ edge)
{
    int gid = blockIdx.x * 256 + threadIdx.x;   // [0, 262144)
    int i = gid >> 8;
    int jc = (gid & 255) << 2;
    float4 s = *(const float4*)(sim + i * NN + jc);
    float4 w = *(const float4*)(cinv + jc);
    float4 o;
    o.x = (s.x + (i == jc + 0 ? 1.f : 0.f) + 1e-6f) * w.x;
    o.y = (s.y + (i == jc + 1 ? 1.f : 0.f) + 1e-6f) * w.y;
    o.z = (s.z + (i == jc + 2 ? 1.f : 0.f) + 1e-6f) * w.z;
    o.w = (s.w + (i == jc + 3 ? 1.f : 0.f) + 1e-6f) * w.w;
    *(float4*)(edge + i * NN + jc) = o;
}

extern "C" void kernel_launch(void* const* d_in, const int* in_sizes, int n_in,
                              void* d_out, int out_size, void* d_ws, size_t ws_size,
                              hipStream_t stream)
{
    const float* feat = (const float*)d_in[0];
    const float* W0   = (const float*)d_in[1];
    const float* g0   = (const float*)d_in[2];
    const float* b0   = (const float*)d_in[3];
    const float* m0   = (const float*)d_in[4];
    const float* v0   = (const float*)d_in[5];
    const float* W1   = (const float*)d_in[6];
    const float* g1   = (const float*)d_in[7];
    const float* b1   = (const float*)d_in[8];
    const float* m1   = (const float*)d_in[9];
    const float* v1   = (const float*)d_in[10];
    const float* Wout = (const float*)d_in[11];
    const float* bout = (const float*)d_in[12];
    char* ws = (char*)d_ws;
    float* edge = (float*)d_out;
    float* sim  = edge + NN * NN;
    float* cinv = (float*)(ws + WS_CINV);
    float* part = (float*)(ws + WS_PART);

    prep_kernel<<<dim3(170), dim3(256), 0, stream>>>(
        W0, g0, b0, m0, v0, W1, g1, b1, m1, v1, Wout, ws);
    edgenet_main<<<dim3(2080), dim3(256), 0, stream>>>(feat, ws, bout, sim);
    colsum_kernel<<<dim3(16, 16), dim3(256), 0, stream>>>(sim, part);
    finalize_kernel<<<dim3(4), dim3(256), 0, stream>>>(part, cinv);
    edge_kernel<<<dim3(1024), dim3(256), 0, stream>>>(sim, cinv, edge);
}